// Round 10
// baseline (115.207 us; speedup 1.0000x reference)
//
#include <hip/hip_runtime.h>

#define DEV __device__ __forceinline__

typedef unsigned short u16;
typedef __attribute__((ext_vector_type(8))) __bf16 bf16x8;
typedef __attribute__((ext_vector_type(4))) float f32x4;
typedef __attribute__((ext_vector_type(8))) unsigned short u16x8;

DEV u16 f2bf(float f) {
  unsigned u = __builtin_bit_cast(unsigned, f);
  u += 0x7fffu + ((u >> 16) & 1u);
  return (u16)(u >> 16);
}
DEV float bf2f(u16 h) {
  unsigned u = ((unsigned)h) << 16;
  return __builtin_bit_cast(float, u);
}

DEV void gl_lds16(const void* gp, void* lp) {
  __builtin_amdgcn_global_load_lds(
      (__attribute__((address_space(1))) void*)(void*)gp,
      (__attribute__((address_space(3))) void*)lp, 16, 0, 0);
}

DEV u16x8 pack8(float4 a, float4 b) {
  u16x8 o;
  o[0] = f2bf(a.x); o[1] = f2bf(a.y); o[2] = f2bf(a.z); o[3] = f2bf(a.w);
  o[4] = f2bf(b.x); o[5] = f2bf(b.y); o[6] = f2bf(b.z); o[7] = f2bf(b.w);
  return o;
}

// ---------------- prep: a = tanh(a_raw); wq = [b;d] bf16; c -> bf16 --------------
__global__ __launch_bounds__(256) void prep_k(const float* __restrict__ a_raw,
                                              const float* __restrict__ b,
                                              const float* __restrict__ c,
                                              const float* __restrict__ d,
                                              float* __restrict__ af,
                                              u16* __restrict__ wq,
                                              u16* __restrict__ cw) {
  int i = blockIdx.x * 256 + threadIdx.x;
  if (i < 256) af[i] = tanhf(a_raw[i]);
  wq[i] = f2bf(b[i]);
  wq[65536 + i] = f2bf(d[i]);
  cw[i] = f2bf(c[i]);
}

// ---------------- gemm1: [Bu|Ud] = u @ [b;d]^T + quarter-chunk carries ----------
// 512 blocks (ALL co-resident at 2 blocks/CU), 512 thr / 8 waves (2x4), block
// tile 128x512, wave tile 64x128 (acc[4][8]). A: fp32 u reg-staged -> bf16 ->
// swizzled LDS (R2-verified map; convu/ubf eliminated). B: wq via gl_lds with
// pre-swizzled source (R3-verified). Outputs: cols 0-255 -> bu (R7-verified
// tile-local quarter-major layout) + quarter carries; cols 256-511 -> ud plain.
__global__ __launch_bounds__(512, 2) void gemm1_k(const float* __restrict__ u,
                                                  const u16* __restrict__ wq,
                                                  const float* __restrict__ af,
                                                  u16* __restrict__ bu,
                                                  u16* __restrict__ ud,
                                                  float* __restrict__ carry4) {
  __shared__ u16 As[128 * 64];   // 16 KB, swizzled
  __shared__ u16 Bs[512 * 64];   // 64 KB, swizzled
  const int tid = threadIdx.x;
  const int lane = tid & 63;
  const int wid = tid >> 6;
  const int wr = wid >> 2, wc = wid & 3;   // wave tile: rows wr*64, cols wc*128
  const size_t row0 = (size_t)blockIdx.x * 128;

  const int arow = tid >> 2;        // 0..127
  const int ak0 = (tid & 3) * 16;   // k offset of this thread's 16 floats
  const int s0 = (tid & 3) * 2;     // first of 2 A slots

  f32x4 acc[4][8];
  const f32x4 zero = {0.f, 0.f, 0.f, 0.f};
#pragma unroll
  for (int i = 0; i < 4; ++i)
#pragma unroll
    for (int j = 0; j < 8; ++j) acc[i][j] = zero;

#pragma unroll
  for (int kt = 0; kt < 4; ++kt) {
    const int kb = kt * 64;
    // A: 16 fp32 per thread
    const float* up = u + (row0 + arow) * 256 + kb + ak0;
    float4 f0 = *reinterpret_cast<const float4*>(up);
    float4 f1 = *reinterpret_cast<const float4*>(up + 4);
    float4 f2 = *reinterpret_cast<const float4*>(up + 8);
    float4 f3 = *reinterpret_cast<const float4*>(up + 12);
    // B: 8 gl_lds per thread (512 rows x 64 k)
#pragma unroll
    for (int r = 0; r < 8; ++r) {
      int wrow = r * 64 + (tid >> 3);
      int sc = (tid & 7) ^ (wrow & 7);
      gl_lds16(wq + (size_t)wrow * 256 + kb + sc * 8,
               (char*)Bs + r * 8192 + wid * 1024);
    }
    // A: convert + swizzled LDS write (R2-verified convention)
    *reinterpret_cast<u16x8*>(&As[arow * 64 + ((s0) ^ (arow & 7)) * 8]) = pack8(f0, f1);
    *reinterpret_cast<u16x8*>(&As[arow * 64 + ((s0 + 1) ^ (arow & 7)) * 8]) = pack8(f2, f3);
    __syncthreads();
#pragma unroll
    for (int kk = 0; kk < 2; ++kk) {
      const int ks = kk * 4 + (lane >> 4);
      bf16x8 afr[4];
#pragma unroll
      for (int mi = 0; mi < 4; ++mi) {
        int ar = wr * 64 + mi * 16 + (lane & 15);
        afr[mi] = *reinterpret_cast<const bf16x8*>(&As[ar * 64 + (ks ^ (ar & 7)) * 8]);
      }
#pragma unroll
      for (int nh = 0; nh < 2; ++nh) {
        bf16x8 bfr[4];
#pragma unroll
        for (int nj = 0; nj < 4; ++nj) {
          int br = wc * 128 + (nh * 4 + nj) * 16 + (lane & 15);
          bfr[nj] = *reinterpret_cast<const bf16x8*>(&Bs[br * 64 + (ks ^ (br & 7)) * 8]);
        }
#pragma unroll
        for (int mi = 0; mi < 4; ++mi)
#pragma unroll
          for (int nj = 0; nj < 4; ++nj)
            acc[mi][nh * 4 + nj] = __builtin_amdgcn_mfma_f32_16x16x32_bf16(
                afr[mi], bfr[nj], acc[mi][nh * 4 + nj], 0, 0, 0);
      }
    }
    if (kt < 3) __syncthreads();
  }

  const size_t t2 = (size_t)blockIdx.x * 2 + wr;   // 64-row chunk index

  if (wc < 2) {
    // ---- bu epilogue: tile-local quarter-major swizzled (R7-verified math) ----
#pragma unroll
    for (int mi = 0; mi < 4; ++mi) {
      int rbase = mi * 16 + (lane >> 4) * 4;
#pragma unroll
      for (int ni = 0; ni < 8; ++ni) {
        int col = wc * 128 + ni * 16 + (lane & 15);   // 0..255
        int colpart = (col >> 6) * 4096 + (col & 7);
        int sl = (col >> 3) & 7;
#pragma unroll
        for (int q = 0; q < 4; ++q) {
          int r = rbase + q;
          bu[t2 * 16384 + colpart + r * 64 + ((sl ^ (r & 7)) * 8)] = f2bf(acc[mi][ni][q]);
        }
      }
    }
    // ---- quarter carries (R7-verified) ----
    const int tb = (lane >> 4) * 4;
#pragma unroll
    for (int ni = 0; ni < 8; ++ni) {
      int col = wc * 128 + ni * 16 + (lane & 15);
      float a = af[col];
      float c2 = a * a, c4 = c2 * c2, c8 = c4 * c4, a12 = c8 * c4;
      float base = (tb == 0) ? a12 : (tb == 4) ? c8 : (tb == 8) ? c4 : 1.0f;
#pragma unroll
      for (int mi = 0; mi < 4; ++mi) {
        float p = base, sq = 0.f;
#pragma unroll
        for (int q = 3; q >= 0; --q) {
          sq = fmaf(p, acc[mi][ni][q], sq);
          if (q) p *= a;
        }
        sq += __shfl_xor(sq, 16, 64);
        sq += __shfl_xor(sq, 32, 64);
        if ((lane >> 4) == 0) carry4[t2 * 1024 + mi * 256 + col] = sq;
      }
    }
  } else {
    // ---- ud epilogue: plain row-major bf16 (R3-verified pattern) ----
#pragma unroll
    for (int mi = 0; mi < 4; ++mi) {
      int rbase = mi * 16 + (lane >> 4) * 4;
#pragma unroll
      for (int ni = 0; ni < 8; ++ni) {
        int cold = (wc - 2) * 128 + ni * 16 + (lane & 15);   // 0..255
#pragma unroll
        for (int q = 0; q < 4; ++q)
          ud[(t2 * 64 + rbase + q) * 256 + cold] = f2bf(acc[mi][ni][q]);
      }
    }
  }
}

// ---------------- scan2: exclusive scan of quarter-carries (a^16 steps) ---------
__global__ __launch_bounds__(256) void scan2_k(const float* __restrict__ carry4,
                                               const float* __restrict__ af,
                                               float* __restrict__ initb4) {
  int b = blockIdx.x;  // 16
  int s = threadIdx.x;
  float a = af[s];
  float a16 = a * a; a16 = a16 * a16; a16 = a16 * a16; a16 = a16 * a16;  // a^16
  float x = 0.f;
  size_t base = (size_t)b * 64 * 1024 + s;
  float c0 = carry4[base], c1 = carry4[base + 256],
        c2 = carry4[base + 512], c3 = carry4[base + 768];
  for (int k = 0; k < 64; ++k) {
    size_t idx = base + (size_t)k * 1024;
    float n0 = 0.f, n1 = 0.f, n2 = 0.f, n3 = 0.f;
    if (k < 63) {
      size_t nx = idx + 1024;
      n0 = carry4[nx]; n1 = carry4[nx + 256]; n2 = carry4[nx + 512]; n3 = carry4[nx + 768];
    }
    initb4[idx] = x;        x = fmaf(a16, x, c0);
    initb4[idx + 256] = x;  x = fmaf(a16, x, c1);
    initb4[idx + 512] = x;  x = fmaf(a16, x, c2);
    initb4[idx + 768] = x;  x = fmaf(a16, x, c3);
    c0 = n0; c1 = n1; c2 = n2; c3 = n3;
  }
}

// ---------------- gemm2: y = xs@c^T + Ud, tile 64x128, K=256 only ---------------
// grid (2, 1024). 512 thr, 8 waves (2x4), wave tile 32x32. LDS 64KB: XS 32KB
// (quarter-major xs) + CS[2] 32KB (c K-tiles, dbuf). acc initialized from ud
// (R3-verified). 4 K-steps, one barrier each.
__global__ __launch_bounds__(512, 4) void gemm2_k(const u16* __restrict__ bu,
                                                  const u16* __restrict__ cw,
                                                  const u16* __restrict__ ud,
                                                  const float* __restrict__ af,
                                                  const float* __restrict__ initb4,
                                                  float* __restrict__ y) {
  __shared__ u16 XS[64 * 256];
  __shared__ u16 CS[2 * 128 * 64];
  const int tid = threadIdx.x;
  const int lane = tid & 63;
  const int wid = tid >> 6;
  const int wr = wid >> 2, wc = wid & 3;
  const int by = blockIdx.y;
  const int col0 = blockIdx.x * 128;

#define G2_CS_STAGE(kbv, bufv)                                               \
  {                                                                          \
    _Pragma("unroll") for (int rr = 0; rr < 2; ++rr) {                       \
      int brow = rr * 64 + (tid >> 3);                                       \
      int sc = (tid & 7) ^ (brow & 7);                                       \
      gl_lds16(cw + (size_t)(col0 + brow) * 256 + (kbv) + sc * 8,            \
               (char*)CS + (bufv)*16384 + rr * 8192 + wid * 1024);           \
    }                                                                        \
  }

  // prologue: bu tile (linear; pre-laid-out) + c k=0 into CS[0]
  const char* src = (const char*)bu + (size_t)by * 32768;
#pragma unroll
  for (int j = 0; j < 4; ++j)
    gl_lds16(src + j * 8192 + tid * 16, (char*)XS + j * 8192 + wid * 1024);
  G2_CS_STAGE(0, 0);
  __syncthreads();

  G2_CS_STAGE(64, 1);  // c k=64 flies during recon

  // ---- recon: 2 chains x 16 steps, 8-wide segments (R9-verified) ----
  {
    const int s = tid & 255;
    const int pair = tid >> 8;
    const float a = af[s];
    const int colpart = (s >> 6) * 4096 + (s & 7);
    const int sl = (s >> 3) & 7;
    float x1 = initb4[(size_t)by * 1024 + (pair * 2) * 256 + s];
    float x2 = initb4[(size_t)by * 1024 + (pair * 2 + 1) * 256 + s];
#define SEG(xv, rb0)                                                          \
  {                                                                           \
    float v[8];                                                               \
    _Pragma("unroll") for (int t = 0; t < 8; ++t) {                           \
      int r = (rb0) + t;                                                      \
      v[t] = bf2f(XS[colpart + r * 64 + ((sl ^ (r & 7)) * 8)]);               \
    }                                                                         \
    _Pragma("unroll") for (int t = 0; t < 8; ++t) {                           \
      xv = fmaf(a, xv, v[t]); v[t] = xv;                                      \
    }                                                                         \
    _Pragma("unroll") for (int t = 0; t < 8; ++t) {                           \
      int r = (rb0) + t;                                                      \
      XS[colpart + r * 64 + ((sl ^ (r & 7)) * 8)] = f2bf(v[t]);               \
    }                                                                         \
  }
    SEG(x1, pair * 32 + 0);
    SEG(x1, pair * 32 + 8);
    SEG(x2, pair * 32 + 16);
    SEG(x2, pair * 32 + 24);
#undef SEG
  }

  // ---- acc init from ud (global loads fly while waiting at the barrier) ----
  f32x4 acc[2][2];
#pragma unroll
  for (int mi = 0; mi < 2; ++mi) {
    int rlb = wr * 32 + mi * 16 + (lane >> 4) * 4;
#pragma unroll
    for (int ni = 0; ni < 2; ++ni) {
      int col = col0 + wc * 32 + ni * 16 + (lane & 15);
#pragma unroll
      for (int q = 0; q < 4; ++q)
        acc[mi][ni][q] = bf2f(ud[((size_t)by * 64 + rlb + q) * 256 + col]);
    }
  }
  __syncthreads();  // recon visible; CS[1] drained

  // ---- K loop: 4 steps of 64 over c ----
#pragma unroll
  for (int kt = 0; kt < 4; ++kt) {
    const u16* CSb = CS + (kt & 1) * 8192;       // u16 units per buffer
    const u16* XSq = XS + kt * 4096;             // u16 units per quarter
#pragma unroll
    for (int kk = 0; kk < 2; ++kk) {
      const int ksl = kk * 4 + (lane >> 4);
      bf16x8 afr[2], bfr[2];
#pragma unroll
      for (int mi = 0; mi < 2; ++mi) {
        int ar = wr * 32 + mi * 16 + (lane & 15);
        afr[mi] = *reinterpret_cast<const bf16x8*>(&XSq[ar * 64 + ((ksl ^ (ar & 7)) * 8)]);
      }
#pragma unroll
      for (int ni = 0; ni < 2; ++ni) {
        int nr = wc * 32 + ni * 16 + (lane & 15);
        bfr[ni] = *reinterpret_cast<const bf16x8*>(&CSb[nr * 64 + ((ksl ^ (nr & 7)) * 8)]);
      }
#pragma unroll
      for (int mi = 0; mi < 2; ++mi)
#pragma unroll
        for (int ni = 0; ni < 2; ++ni)
          acc[mi][ni] = __builtin_amdgcn_mfma_f32_16x16x32_bf16(
              afr[mi], bfr[ni], acc[mi][ni], 0, 0, 0);
    }
    if (kt < 3) {
      __syncthreads();                    // readers done with CS[kt&1]; drains prior stage
      if (kt < 2) G2_CS_STAGE((kt + 2) * 64, kt & 1);  // overlaps next step's compute
    }
  }

  // ---- epilogue ----
#pragma unroll
  for (int mi = 0; mi < 2; ++mi) {
    int rlb = wr * 32 + mi * 16 + (lane >> 4) * 4;
#pragma unroll
    for (int ni = 0; ni < 2; ++ni) {
      int col = col0 + wc * 32 + ni * 16 + (lane & 15);
#pragma unroll
      for (int q = 0; q < 4; ++q)
        y[((size_t)by * 64 + rlb + q) * 256 + col] = acc[mi][ni][q];
    }
  }
}

extern "C" void kernel_launch(void* const* d_in, const int* in_sizes, int n_in,
                              void* d_out, int out_size, void* d_ws, size_t ws_size,
                              hipStream_t stream) {
  const float* u = (const float*)d_in[0];
  const float* a_raw = (const float*)d_in[1];
  const float* b = (const float*)d_in[2];
  const float* c = (const float*)d_in[3];
  const float* d = (const float*)d_in[4];
  float* y = (float*)d_out;
  char* ws = (char*)d_ws;

  const size_t MB = 1u << 20;
  float* af = (float*)(ws);                       // 1 KB
  u16* wq = (u16*)(ws + 4096);                    // 256 KB ([b;d] stacked)
  u16* cw = (u16*)(ws + 4096 + 262144);           // 128 KB
  u16* bu = (u16*)(ws + 1 * MB);                  // 32 MB (tile quarter-major)
  u16* ud = (u16*)(ws + 33 * MB);                 // 32 MB (plain row-major)
  float* carry4 = (float*)(ws + 65 * MB);         // 4 MB
  float* initb4 = (float*)(ws + 69 * MB);         // 4 MB

  prep_k<<<256, 256, 0, stream>>>(a_raw, b, c, d, af, wq, cw);
  gemm1_k<<<512, 512, 0, stream>>>(u, wq, af, bu, ud, carry4);
  scan2_k<<<16, 256, 0, stream>>>(carry4, af, initb4);
  gemm2_k<<<dim3(2, 1024), 512, 0, stream>>>(bu, cw, ud, af, initb4, y);
}